// Round 13
// baseline (289.531 us; speedup 1.0000x reference)
//
#include <hip/hip_runtime.h>
#include <hip/hip_bf16.h>
#include <hip/hip_fp16.h>

#define H 128           // H_IN == H_OUT == 128
#define BW 128          // nodes per coarse bucket
#define BSH 7           // log2(BW)
#define NB 256          // edge-partition blocks
#define TK 32           // p2 tile width (buckets per block)

typedef __attribute__((ext_vector_type(8))) short short8;
typedef __attribute__((ext_vector_type(4))) float f32x4;

__device__ inline unsigned short f2bf(float f) {
    union { float f; unsigned int u; } v; v.f = f;
    unsigned int r = (v.u + 0x7fffu + ((v.u >> 16) & 1u)) >> 16;
    return (unsigned short)r;
}
__device__ inline float bf2f(unsigned short h) {
    union { unsigned int u; float f; } v; v.u = ((unsigned int)h) << 16;
    return v.f;
}

// ---------------------------------------------------------------------------
// K1 fused (proven): per-row u8 quant (blocks 0..qb-1), W-pack (blocks 0..7),
// p1 LDS histogram (blocks qb..). LDS atomics only -- NO global atomics.
__global__ __launch_bounds__(256) void quant_hist_kernel(const float* __restrict__ x,
                                                         const float* __restrict__ Wc,
                                                         const float* __restrict__ Ws,
                                                         const int* __restrict__ ei,
                                                         uint* __restrict__ xq,
                                                         float* __restrict__ invs,
                                                         short8* __restrict__ wp,
                                                         int* __restrict__ counts,
                                                         int N, int E, int nbu,
                                                         int chunk, int qb) {
    __shared__ int h[1024];
    if (blockIdx.x >= qb) {
        const int b = blockIdx.x - qb;
        for (int i = threadIdx.x; i < nbu; i += 256) h[i] = 0;
        __syncthreads();
        const int lo = b * chunk;
        const int hi = min(E, lo + chunk);
        for (int e = lo + threadIdx.x; e < hi; e += 256)
            atomicAdd(&h[ei[E + e] >> BSH], 1);
        __syncthreads();
        for (int i = threadIdx.x; i < nbu; i += 256) counts[b * nbu + i] = h[i];
        return;
    }
    int node = blockIdx.x * 8 + (threadIdx.x >> 5);
    if (node < N) {
        int l32 = threadIdx.x & 31;
        float4 v = ((const float4*)x)[node * 32 + l32];
        float m = fmaxf(fmaxf(fabsf(v.x), fabsf(v.y)), fmaxf(fabsf(v.z), fabsf(v.w)));
        #pragma unroll
        for (int mk = 1; mk < 32; mk <<= 1) m = fmaxf(m, __shfl_xor(m, mk));
        m = fmaxf(m, 1e-30f);
        float s = 127.0f / m;
        int q0 = min(255, max(0, (int)rintf(v.x * s) + 128));
        int q1 = min(255, max(0, (int)rintf(v.y * s) + 128));
        int q2 = min(255, max(0, (int)rintf(v.z * s) + 128));
        int q3 = min(255, max(0, (int)rintf(v.w * s) + 128));
        xq[node * 32 + l32] = (uint)q0 | ((uint)q1 << 8) | ((uint)q2 << 16) | ((uint)q3 << 24);
        if (l32 == 0) invs[node] = m / 127.0f;
    }
    if (blockIdx.x < 8) {
        int t = blockIdx.x * 256 + threadIdx.x;   // 0..2047
        int lane = t & 63;
        int nt = (t >> 6) & 7;
        int ks = t >> 9;
        int kbase = ks * 32 + (lane >> 4) * 8;
        int col = nt * 16 + (lane & 15);
        short8 whc, whs, wls;
        #pragma unroll
        for (int j = 0; j < 8; ++j) {
            float wc = Wc[(kbase + j) * H + col];
            float ws = Ws[(kbase + j) * H + col];
            unsigned short hc = f2bf(wc);
            unsigned short hs = f2bf(ws);
            whc[j] = (short)hc;
            whs[j] = (short)hs;
            wls[j] = (short)f2bf(ws - bf2f(hs));
        }
        int base = (ks * 8 + nt) * 64 + lane;
        wp[base] = whc;
        wp[2048 + base] = whs;
        wp[4096 + base] = wls;
    }
}

// ---------------------------------------------------------------------------
// P2 (coalesced tiled form, proven round-10)
__global__ __launch_bounds__(256) void p2_scan(const int* __restrict__ counts,
                                               int* __restrict__ scanned,
                                               int* __restrict__ btot, int nbu) {
    __shared__ int tile[NB][TK + 1];
    __shared__ int segsum[8][TK + 1];
    const int tl = threadIdx.x & 31;
    const int tw = threadIdx.x >> 5;
    const int k = blockIdx.x * TK + tl;
    const bool kok = k < nbu;
    for (int r = tw; r < NB; r += 8)
        tile[r][tl] = kok ? counts[r * nbu + k] : 0;
    __syncthreads();
    const int base = tw * 32;
    int s = 0;
    #pragma unroll
    for (int i = 0; i < 32; ++i) s += tile[base + i][tl];
    segsum[tw][tl] = s;
    __syncthreads();
    int run = 0;
    for (int q = 0; q < tw; ++q) run += segsum[q][tl];
    if (kok) {
        for (int i = 0; i < 32; ++i) {
            int cur = tile[base + i][tl];
            scanned[(base + i) * nbu + k] = run;
            run += cur;
        }
        if (tw == 7) btot[k] = run;
    }
}

// ---------------------------------------------------------------------------
// P5: scatter packed edges into exact slots (proven; no global atomics).
__global__ __launch_bounds__(256) void p5_scatter(const int* __restrict__ ei,
                                                  const int* __restrict__ btot,
                                                  const int* __restrict__ scanned,
                                                  int* __restrict__ tmp,
                                                  int* __restrict__ cstart,
                                                  int E, int nbu, int chunk) {
    __shared__ int sc[1024];
    __shared__ int part[256];
    __shared__ int lb[1024];
    const int t = threadIdx.x;
    const int b = blockIdx.x;
    const int base = t * 4;
    int v0 = (base + 0 < nbu) ? btot[base + 0] : 0;
    int v1 = (base + 1 < nbu) ? btot[base + 1] : 0;
    int v2 = (base + 2 < nbu) ? btot[base + 2] : 0;
    int v3 = (base + 3 < nbu) ? btot[base + 3] : 0;
    int s1 = v0 + v1, s2 = s1 + v2, s3 = s2 + v3;
    part[t] = s3;
    __syncthreads();
    for (int off = 1; off < 256; off <<= 1) {
        int a = (t >= off) ? part[t - off] : 0;
        __syncthreads();
        part[t] += a;
        __syncthreads();
    }
    int add = (t > 0) ? part[t - 1] : 0;
    sc[base + 0] = add;
    sc[base + 1] = add + v0;
    sc[base + 2] = add + s1;
    sc[base + 3] = add + s2;
    __syncthreads();
    if (b == 0) {
        for (int k = t; k < nbu; k += 256) cstart[k] = sc[k];
        if (t == 0) cstart[nbu] = E;
    }
    for (int k = t; k < nbu; k += 256) lb[k] = sc[k] + scanned[b * nbu + k];
    __syncthreads();
    const int lo = b * chunk;
    const int hi = min(E, lo + chunk);
    for (int e = lo + t; e < hi; e += 256) {
        int s = ei[e], d = ei[E + e];
        int slot = atomicAdd(&lb[d >> BSH], 1);
        tmp[slot] = ((d & (BW - 1)) << 17) | s;
    }
}

// ---------------------------------------------------------------------------
// csrOne (proven): per bucket, LDS histogram + scan -> rstart/dinv/ainv/selfw,
// then in-bucket scatter tmp -> entries.
__global__ __launch_bounds__(256) void csr_kernel(const int* __restrict__ tmp,
                                                  const int* __restrict__ cstart,
                                                  const float* __restrict__ invs,
                                                  int* __restrict__ entries,
                                                  int* __restrict__ rstart,
                                                  float* __restrict__ dinv,
                                                  float* __restrict__ ainv,
                                                  float* __restrict__ selfw,
                                                  int N, int E) {
    __shared__ int ldeg[BW];
    __shared__ int lscan[BW];
    __shared__ int lcur[BW];
    const int b = blockIdx.x;
    const int nstart = b << BSH;
    const int estart = cstart[b];
    const int eend = cstart[b + 1];
    const int t = threadIdx.x;

    if (t < BW) ldeg[t] = 0;
    __syncthreads();
    for (int i = estart + t; i < eend; i += 256)
        atomicAdd(&ldeg[(tmp[i] >> 17) & (BW - 1)], 1);
    __syncthreads();
    if (t < BW) lscan[t] = ldeg[t];
    __syncthreads();
    #pragma unroll
    for (int off = 1; off < BW; off <<= 1) {
        int a = 0;
        if (t < BW && t >= off) a = lscan[t - off];
        __syncthreads();
        if (t < BW) lscan[t] += a;
        __syncthreads();
    }
    if (t < BW) {
        int excl = lscan[t] - ldeg[t];
        lcur[t] = excl;
        int n = nstart + t;
        if (n < N) {
            float iv = invs[n];
            float dv = rsqrtf((float)ldeg[t] + 2.0f);
            rstart[n] = estart + excl;
            dinv[n] = dv;
            ainv[n] = dv * iv;
            selfw[n] = 2.0f * dv * dv * iv;
        }
    }
    __syncthreads();
    for (int i = estart + t; i < eend; i += 256) {
        int v = tmp[i];
        int sl = atomicAdd(&lcur[(v >> 17) & (BW - 1)], 1);
        entries[estart + sl] = v & 0x1FFFF;
    }
    if (b == 0 && t == 0) rstart[N] = E;
}

// ---------------------------------------------------------------------------
// FUSED agg + gemm, v2. 64 nodes per block (= gemm row tile).
// Round-11 failure analysis applied: LDS is ONLY zs (16KB, XOR-swizzled) --
// bsm staging removed, wp read straight from L2 (round-3 pattern, ~7us cost)
// -> blocks/CU = min(160/16, 32/4) = 8, restoring agg-phase occupancy.
// Phase 1 = round-12 agg loop verbatim (uniform predicate + full unroll).
// Phase 2 = gemm with za from zs, B-operands from L2.
__global__ __launch_bounds__(256) void agg_gemm_kernel(const int* __restrict__ entries,
                                                       const int* __restrict__ rstart,
                                                       const float* __restrict__ dinv,
                                                       const float* __restrict__ ainv,
                                                       const float* __restrict__ selfw,
                                                       const uint* __restrict__ xq,
                                                       const float* __restrict__ x,
                                                       const short8* __restrict__ wp,
                                                       const float* __restrict__ bc,
                                                       const float* __restrict__ bsk,
                                                       float* __restrict__ out, int N) {
    __shared__ uint zs[4096];      // 64 rows x 64 dwords (256B), swizzled; 16KB
    const int tid = threadIdx.x;
    const int l16 = tid & 15;
    const int qid = tid >> 4;      // quarter id 0..15
    const uint2* x2 = (const uint2*)xq;

    // ---- Phase 1: aggregate 4 nodes per quarter-wave ----
    #pragma unroll 1
    for (int rep = 0; rep < 4; ++rep) {
        const int zrow = rep * 16 + qid;
        const int node = blockIdx.x * 64 + zrow;
        if (node < N) {
            int start = rstart[node];
            int end = rstart[node + 1];
            float dd = dinv[node];
            float sw = selfw[node];
            uint2 qs = x2[node * 16 + l16];

            float a0 = 0.f, a1 = 0.f, a2 = 0.f, a3 = 0.f;
            float a4 = 0.f, a5 = 0.f, a6 = 0.f, a7 = 0.f;
            float sumw = 0.f;

            for (int c = start; c < end; c += 16) {
                int rem = end - c;
                int src = 0;
                float w = 0.f;
                if (l16 < rem) {
                    src = entries[c + l16];
                    w = ainv[src] * dd;
                }
                #pragma unroll
                for (int j = 0; j < 16; ++j) {
                    if (c + j < end) {
                        int ss = __shfl(src, j, 16);
                        float wv = __shfl(w, j, 16);
                        uint2 q = x2[ss * 16 + l16];
                        sumw += wv;
                        a0 += wv * (float)(q.x & 0xffu);
                        a1 += wv * (float)((q.x >> 8) & 0xffu);
                        a2 += wv * (float)((q.x >> 16) & 0xffu);
                        a3 += wv * (float)(q.x >> 24);
                        a4 += wv * (float)(q.y & 0xffu);
                        a5 += wv * (float)((q.y >> 8) & 0xffu);
                        a6 += wv * (float)((q.y >> 16) & 0xffu);
                        a7 += wv * (float)(q.y >> 24);
                    }
                }
            }

            sumw += sw;
            a0 += sw * (float)(qs.x & 0xffu);
            a1 += sw * (float)((qs.x >> 8) & 0xffu);
            a2 += sw * (float)((qs.x >> 16) & 0xffu);
            a3 += sw * (float)(qs.x >> 24);
            a4 += sw * (float)(qs.y & 0xffu);
            a5 += sw * (float)((qs.y >> 8) & 0xffu);
            a6 += sw * (float)((qs.y >> 16) & 0xffu);
            a7 += sw * (float)(qs.y >> 24);

            float off = 128.f * sumw;
            uint4 o;
            o.x = (uint)f2bf(a0 - off) | ((uint)f2bf(a1 - off) << 16);
            o.y = (uint)f2bf(a2 - off) | ((uint)f2bf(a3 - off) << 16);
            o.z = (uint)f2bf(a4 - off) | ((uint)f2bf(a5 - off) << 16);
            o.w = (uint)f2bf(a6 - off) | ((uint)f2bf(a7 - off) << 16);
            // swizzled store: bijective within the row, 16B-aligned
            *(uint4*)&zs[zrow * 64 + ((l16 * 4) ^ ((zrow & 7) * 4))] = o;
        }
    }
    __syncthreads();

    // ---- Phase 2: gemm (za from LDS, B-planes from L2) ----
    const int lane = tid & 63;
    const int wave = tid >> 6;
    const int m = lane & 15;
    const int quad = lane >> 4;
    const int row = blockIdx.x * 64 + wave * 16 + m;
    const bool rowok = row < N;
    const int zr = wave * 16 + m;

    f32x4 acc[8];
    #pragma unroll
    for (int i = 0; i < 8; ++i) acc[i] = (f32x4){0.f, 0.f, 0.f, 0.f};

    #pragma unroll
    for (int ks = 0; ks < 4; ++ks) {
        const int k0 = ks * 32 + quad * 8;
        // za from LDS (swizzle matches phase-1 store; garbage for rows >= N
        // is harmless -- MFMA rows are independent and not stored)
        short8 za = *(const short8*)&zs[zr * 64 + ((ks * 16 + quad * 4) ^ ((zr & 7) * 4))];
        short8 xa_h = {0, 0, 0, 0, 0, 0, 0, 0};
        short8 xa_l = {0, 0, 0, 0, 0, 0, 0, 0};
        if (rowok) {
            float4 a = *(const float4*)&x[row * H + k0];
            float4 b = *(const float4*)&x[row * H + k0 + 4];
            float xv[8] = {a.x, a.y, a.z, a.w, b.x, b.y, b.z, b.w};
            #pragma unroll
            for (int j = 0; j < 8; ++j) {
                unsigned short h = f2bf(xv[j]);
                xa_h[j] = (short)h;
                xa_l[j] = (short)f2bf(xv[j] - bf2f(h));
            }
        }
        #pragma unroll
        for (int nt = 0; nt < 8; ++nt) {
            int base = (ks * 8 + nt) * 64 + lane;
            short8 bch = wp[base];
            short8 bsh = wp[2048 + base];
            short8 bsl = wp[4096 + base];
            acc[nt] = __builtin_amdgcn_mfma_f32_16x16x32_bf16(za, bch, acc[nt], 0, 0, 0);
            acc[nt] = __builtin_amdgcn_mfma_f32_16x16x32_bf16(xa_h, bsh, acc[nt], 0, 0, 0);
            acc[nt] = __builtin_amdgcn_mfma_f32_16x16x32_bf16(xa_l, bsh, acc[nt], 0, 0, 0);
            acc[nt] = __builtin_amdgcn_mfma_f32_16x16x32_bf16(xa_h, bsl, acc[nt], 0, 0, 0);
        }
    }

    const int orow_base = blockIdx.x * 64 + wave * 16 + quad * 4;
    #pragma unroll
    for (int nt = 0; nt < 8; ++nt) {
        int col = nt * 16 + m;
        float bias = bc[col] + bsk[col];
        #pragma unroll
        for (int r = 0; r < 4; ++r) {
            int orow = orow_base + r;
            if (orow < N) {
                float v = acc[nt][r] + bias;
                v = v > 0.f ? v : 0.1f * (__expf(v) - 1.f);
                out[orow * H + col] = v;
            }
        }
    }
}

// ---------------------------------------------------------------------------
extern "C" void kernel_launch(void* const* d_in, const int* in_sizes, int n_in,
                              void* d_out, int out_size, void* d_ws, size_t ws_size,
                              hipStream_t stream) {
    const float* x   = (const float*)d_in[0];
    const int*   ei  = (const int*)d_in[1];
    const float* Wc  = (const float*)d_in[2];
    const float* bc  = (const float*)d_in[3];
    const float* Wsk = (const float*)d_in[4];
    const float* bsk = (const float*)d_in[5];
    float* out = (float*)d_out;

    const int N = in_sizes[0] / H;       // 100000
    const int E = in_sizes[1] / 2;       // 1600000
    const int nbu = (N + BW - 1) / BW;   // 782 coarse buckets (<=1024)
    const int chunk = (E + NB - 1) / NB; // 6250 edges per partition block
    const int qb = (N + 7) / 8;          // quant blocks

    // workspace layout (byte offsets) -- round-10 map; z no longer exists:
    //   0         wp (96KB, pad to 128K)
    //   131072    rstart (N+1 ints)
    //   540672    dinv (N f32)
    //   942080    ainv (N f32)
    //   1343488   selfw (N f32)
    //   1744896   entries (E ints, 6.4MB)
    //   8146944   xq (u8 N*H, 12.8MB)
    //   20971520  invs (N f32)          [quant -> csrOne]
    //   21371520  cstart (nbu+1)        [p5 -> csrOne]
    //   21374784  btot (nbu)            [p2 -> p5]
    //   21377984  counts (NB*nbu)       [hist -> p2]
    //   22178752  scanned (NB*nbu)      [p2 -> p5]
    //   22979520  tmp (E ints, 6.4MB)   [p5 -> csrOne]
    char* w = (char*)d_ws;
    short8*         wp      = (short8*)w;
    int*            rstart  = (int*)(w + 131072);
    float*          dinv    = (float*)(w + 540672);
    float*          ainv    = (float*)(w + 942080);
    float*          selfw   = (float*)(w + 1343488);
    int*            entries = (int*)(w + 1744896);
    uint*           xq      = (uint*)(w + 8146944);
    float*          invs    = (float*)(w + 20971520);
    int*            cstart  = (int*)(w + 21371520);
    int*            btot    = (int*)(w + 21374784);
    int*            counts  = (int*)(w + 21377984);
    int*            scanned = (int*)(w + 22178752);
    int*            tmp     = (int*)(w + 22979520);

    // quant + W-pack + p1 histogram, fused
    quant_hist_kernel<<<qb + NB, 256, 0, stream>>>(x, Wc, Wsk, ei, xq, invs, wp,
                                                   counts, N, E, nbu, chunk, qb);

    // coalesced tiled scan of counts -> scanned + btot
    p2_scan<<<(nbu + TK - 1) / TK, 256, 0, stream>>>(counts, scanned, btot, nbu);

    p5_scatter<<<NB, 256, 0, stream>>>(ei, btot, scanned, tmp, cstart, E, nbu, chunk);

    // single CSR kernel: metrics + in-bucket sort
    csr_kernel<<<nbu, 256, 0, stream>>>(tmp, cstart, invs, entries, rstart,
                                        dinv, ainv, selfw, N, E);

    // fused agg + gemm (v2): z lives only in LDS; wp from L2
    agg_gemm_kernel<<<(N + 63) / 64, 256, 0, stream>>>(entries, rstart, dinv, ainv,
                                                       selfw, xq, x, wp, bc, bsk,
                                                       out, N);
}

// Round 14
// 243.037 us; speedup vs baseline: 1.1913x; 1.1913x over previous
//
#include <hip/hip_runtime.h>
#include <hip/hip_bf16.h>
#include <hip/hip_fp16.h>

#define H 128           // H_IN == H_OUT == 128
#define BW 128          // nodes per coarse bucket
#define BSH 7           // log2(BW)
#define NB 256          // edge-partition blocks
#define TK 32           // p2 tile width (buckets per block)

typedef __attribute__((ext_vector_type(8))) short short8;
typedef __attribute__((ext_vector_type(4))) float f32x4;

__device__ inline unsigned short f2bf(float f) {
    union { float f; unsigned int u; } v; v.f = f;
    unsigned int r = (v.u + 0x7fffu + ((v.u >> 16) & 1u)) >> 16;
    return (unsigned short)r;
}
__device__ inline float bf2f(unsigned short h) {
    union { unsigned int u; float f; } v; v.u = ((unsigned int)h) << 16;
    return v.f;
}

// ---------------------------------------------------------------------------
// K1 fused (proven): per-row u8 quant (blocks 0..qb-1), W-pack (blocks 0..7),
// p1 LDS histogram (blocks qb..). LDS atomics only -- NO global atomics.
__global__ __launch_bounds__(256) void quant_hist_kernel(const float* __restrict__ x,
                                                         const float* __restrict__ Wc,
                                                         const float* __restrict__ Ws,
                                                         const int* __restrict__ ei,
                                                         uint* __restrict__ xq,
                                                         float* __restrict__ invs,
                                                         short8* __restrict__ wp,
                                                         int* __restrict__ counts,
                                                         int N, int E, int nbu,
                                                         int chunk, int qb) {
    __shared__ int h[1024];
    if (blockIdx.x >= qb) {
        const int b = blockIdx.x - qb;
        for (int i = threadIdx.x; i < nbu; i += 256) h[i] = 0;
        __syncthreads();
        const int lo = b * chunk;
        const int hi = min(E, lo + chunk);
        for (int e = lo + threadIdx.x; e < hi; e += 256)
            atomicAdd(&h[ei[E + e] >> BSH], 1);
        __syncthreads();
        for (int i = threadIdx.x; i < nbu; i += 256) counts[b * nbu + i] = h[i];
        return;
    }
    int node = blockIdx.x * 8 + (threadIdx.x >> 5);
    if (node < N) {
        int l32 = threadIdx.x & 31;
        float4 v = ((const float4*)x)[node * 32 + l32];
        float m = fmaxf(fmaxf(fabsf(v.x), fabsf(v.y)), fmaxf(fabsf(v.z), fabsf(v.w)));
        #pragma unroll
        for (int mk = 1; mk < 32; mk <<= 1) m = fmaxf(m, __shfl_xor(m, mk));
        m = fmaxf(m, 1e-30f);
        float s = 127.0f / m;
        int q0 = min(255, max(0, (int)rintf(v.x * s) + 128));
        int q1 = min(255, max(0, (int)rintf(v.y * s) + 128));
        int q2 = min(255, max(0, (int)rintf(v.z * s) + 128));
        int q3 = min(255, max(0, (int)rintf(v.w * s) + 128));
        xq[node * 32 + l32] = (uint)q0 | ((uint)q1 << 8) | ((uint)q2 << 16) | ((uint)q3 << 24);
        if (l32 == 0) invs[node] = m / 127.0f;
    }
    if (blockIdx.x < 8) {
        int t = blockIdx.x * 256 + threadIdx.x;   // 0..2047
        int lane = t & 63;
        int nt = (t >> 6) & 7;
        int ks = t >> 9;
        int kbase = ks * 32 + (lane >> 4) * 8;
        int col = nt * 16 + (lane & 15);
        short8 whc, whs, wls;
        #pragma unroll
        for (int j = 0; j < 8; ++j) {
            float wc = Wc[(kbase + j) * H + col];
            float ws = Ws[(kbase + j) * H + col];
            unsigned short hc = f2bf(wc);
            unsigned short hs = f2bf(ws);
            whc[j] = (short)hc;
            whs[j] = (short)hs;
            wls[j] = (short)f2bf(ws - bf2f(hs));
        }
        int base = (ks * 8 + nt) * 64 + lane;
        wp[base] = whc;
        wp[2048 + base] = whs;
        wp[4096 + base] = wls;
    }
}

// ---------------------------------------------------------------------------
// P2 (coalesced tiled form, proven round-10)
__global__ __launch_bounds__(256) void p2_scan(const int* __restrict__ counts,
                                               int* __restrict__ scanned,
                                               int* __restrict__ btot, int nbu) {
    __shared__ int tile[NB][TK + 1];
    __shared__ int segsum[8][TK + 1];
    const int tl = threadIdx.x & 31;
    const int tw = threadIdx.x >> 5;
    const int k = blockIdx.x * TK + tl;
    const bool kok = k < nbu;
    for (int r = tw; r < NB; r += 8)
        tile[r][tl] = kok ? counts[r * nbu + k] : 0;
    __syncthreads();
    const int base = tw * 32;
    int s = 0;
    #pragma unroll
    for (int i = 0; i < 32; ++i) s += tile[base + i][tl];
    segsum[tw][tl] = s;
    __syncthreads();
    int run = 0;
    for (int q = 0; q < tw; ++q) run += segsum[q][tl];
    if (kok) {
        for (int i = 0; i < 32; ++i) {
            int cur = tile[base + i][tl];
            scanned[(base + i) * nbu + k] = run;
            run += cur;
        }
        if (tw == 7) btot[k] = run;
    }
}

// ---------------------------------------------------------------------------
// P5: scatter packed edges into exact slots (proven; no global atomics).
__global__ __launch_bounds__(256) void p5_scatter(const int* __restrict__ ei,
                                                  const int* __restrict__ btot,
                                                  const int* __restrict__ scanned,
                                                  int* __restrict__ tmp,
                                                  int* __restrict__ cstart,
                                                  int E, int nbu, int chunk) {
    __shared__ int sc[1024];
    __shared__ int part[256];
    __shared__ int lb[1024];
    const int t = threadIdx.x;
    const int b = blockIdx.x;
    const int base = t * 4;
    int v0 = (base + 0 < nbu) ? btot[base + 0] : 0;
    int v1 = (base + 1 < nbu) ? btot[base + 1] : 0;
    int v2 = (base + 2 < nbu) ? btot[base + 2] : 0;
    int v3 = (base + 3 < nbu) ? btot[base + 3] : 0;
    int s1 = v0 + v1, s2 = s1 + v2, s3 = s2 + v3;
    part[t] = s3;
    __syncthreads();
    for (int off = 1; off < 256; off <<= 1) {
        int a = (t >= off) ? part[t - off] : 0;
        __syncthreads();
        part[t] += a;
        __syncthreads();
    }
    int add = (t > 0) ? part[t - 1] : 0;
    sc[base + 0] = add;
    sc[base + 1] = add + v0;
    sc[base + 2] = add + s1;
    sc[base + 3] = add + s2;
    __syncthreads();
    if (b == 0) {
        for (int k = t; k < nbu; k += 256) cstart[k] = sc[k];
        if (t == 0) cstart[nbu] = E;
    }
    for (int k = t; k < nbu; k += 256) lb[k] = sc[k] + scanned[b * nbu + k];
    __syncthreads();
    const int lo = b * chunk;
    const int hi = min(E, lo + chunk);
    for (int e = lo + t; e < hi; e += 256) {
        int s = ei[e], d = ei[E + e];
        int slot = atomicAdd(&lb[d >> BSH], 1);
        tmp[slot] = ((d & (BW - 1)) << 17) | s;
    }
}

// ---------------------------------------------------------------------------
// csrOne (proven): per bucket, LDS histogram + scan -> rstart/dinv/ainv/selfw,
// then in-bucket scatter tmp -> entries.
__global__ __launch_bounds__(256) void csr_kernel(const int* __restrict__ tmp,
                                                  const int* __restrict__ cstart,
                                                  const float* __restrict__ invs,
                                                  int* __restrict__ entries,
                                                  int* __restrict__ rstart,
                                                  float* __restrict__ dinv,
                                                  float* __restrict__ ainv,
                                                  float* __restrict__ selfw,
                                                  int N, int E) {
    __shared__ int ldeg[BW];
    __shared__ int lscan[BW];
    __shared__ int lcur[BW];
    const int b = blockIdx.x;
    const int nstart = b << BSH;
    const int estart = cstart[b];
    const int eend = cstart[b + 1];
    const int t = threadIdx.x;

    if (t < BW) ldeg[t] = 0;
    __syncthreads();
    for (int i = estart + t; i < eend; i += 256)
        atomicAdd(&ldeg[(tmp[i] >> 17) & (BW - 1)], 1);
    __syncthreads();
    if (t < BW) lscan[t] = ldeg[t];
    __syncthreads();
    #pragma unroll
    for (int off = 1; off < BW; off <<= 1) {
        int a = 0;
        if (t < BW && t >= off) a = lscan[t - off];
        __syncthreads();
        if (t < BW) lscan[t] += a;
        __syncthreads();
    }
    if (t < BW) {
        int excl = lscan[t] - ldeg[t];
        lcur[t] = excl;
        int n = nstart + t;
        if (n < N) {
            float iv = invs[n];
            float dv = rsqrtf((float)ldeg[t] + 2.0f);
            rstart[n] = estart + excl;
            dinv[n] = dv;
            ainv[n] = dv * iv;
            selfw[n] = 2.0f * dv * dv * iv;
        }
    }
    __syncthreads();
    for (int i = estart + t; i < eend; i += 256) {
        int v = tmp[i];
        int sl = atomicAdd(&lcur[(v >> 17) & (BW - 1)], 1);
        entries[estart + sl] = v & 0x1FFFF;
    }
    if (b == 0 && t == 0) rstart[N] = E;
}

// ---------------------------------------------------------------------------
// Gather aggregation on u8 x. ONE OCTET (8 lanes x uint4 = 16 features) PER
// NODE. 8 lanes x 16 features = all 128 -> NO cross-lane reduce (the reduce
// was what killed the round-2 octet attempt in 1-node-per-wave geometry).
// vs round-12 quarter geometry: half the gather + shfl instructions per
// edge, 2x independent node-chains per wave (8 vs 4) -> 2x MLP for this
// latency-bound kernel. Accumulators are 16 NAMED scalars (SROA-proof).
// Uniform predicate (c+j<end) keeps the ainv gather off the xq chain.
__global__ __launch_bounds__(256) void agg_kernel(const int* __restrict__ entries,
                                                  const int* __restrict__ rstart,
                                                  const float* __restrict__ dinv,
                                                  const float* __restrict__ ainv,
                                                  const float* __restrict__ selfw,
                                                  const uint* __restrict__ xq,
                                                  unsigned short* __restrict__ z, int N) {
    int node = blockIdx.x * 32 + (threadIdx.x >> 3);
    if (node >= N) return;
    const int l8 = threadIdx.x & 7;
    const uint4* x4 = (const uint4*)xq;   // 16 features per element, 8 per row

    int start = rstart[node];
    int end = rstart[node + 1];
    float dd = dinv[node];
    float sw = selfw[node];
    uint4 qs = x4[node * 8 + l8];

    float a00 = 0.f, a01 = 0.f, a02 = 0.f, a03 = 0.f;
    float a04 = 0.f, a05 = 0.f, a06 = 0.f, a07 = 0.f;
    float a08 = 0.f, a09 = 0.f, a10 = 0.f, a11 = 0.f;
    float a12 = 0.f, a13 = 0.f, a14 = 0.f, a15 = 0.f;
    float sumw = 0.f;

    for (int c = start; c < end; c += 8) {
        int rem = end - c;
        int src = 0;
        float w = 0.f;
        if (l8 < rem) {
            src = entries[c + l8];
            w = ainv[src] * dd;
        }
        #pragma unroll
        for (int j = 0; j < 8; ++j) {
            if (c + j < end) {
                int ss = __shfl(src, j, 8);
                float wv = __shfl(w, j, 8);
                uint4 q = x4[ss * 8 + l8];
                sumw += wv;
                a00 += wv * (float)(q.x & 0xffu);
                a01 += wv * (float)((q.x >> 8) & 0xffu);
                a02 += wv * (float)((q.x >> 16) & 0xffu);
                a03 += wv * (float)(q.x >> 24);
                a04 += wv * (float)(q.y & 0xffu);
                a05 += wv * (float)((q.y >> 8) & 0xffu);
                a06 += wv * (float)((q.y >> 16) & 0xffu);
                a07 += wv * (float)(q.y >> 24);
                a08 += wv * (float)(q.z & 0xffu);
                a09 += wv * (float)((q.z >> 8) & 0xffu);
                a10 += wv * (float)((q.z >> 16) & 0xffu);
                a11 += wv * (float)(q.z >> 24);
                a12 += wv * (float)(q.w & 0xffu);
                a13 += wv * (float)((q.w >> 8) & 0xffu);
                a14 += wv * (float)((q.w >> 16) & 0xffu);
                a15 += wv * (float)(q.w >> 24);
            }
        }
    }

    // self-loop from own quantized row (accumulators complete per lane)
    sumw += sw;
    a00 += sw * (float)(qs.x & 0xffu);
    a01 += sw * (float)((qs.x >> 8) & 0xffu);
    a02 += sw * (float)((qs.x >> 16) & 0xffu);
    a03 += sw * (float)(qs.x >> 24);
    a04 += sw * (float)(qs.y & 0xffu);
    a05 += sw * (float)((qs.y >> 8) & 0xffu);
    a06 += sw * (float)((qs.y >> 16) & 0xffu);
    a07 += sw * (float)(qs.y >> 24);
    a08 += sw * (float)(qs.z & 0xffu);
    a09 += sw * (float)((qs.z >> 8) & 0xffu);
    a10 += sw * (float)((qs.z >> 16) & 0xffu);
    a11 += sw * (float)(qs.z >> 24);
    a12 += sw * (float)(qs.w & 0xffu);
    a13 += sw * (float)((qs.w >> 8) & 0xffu);
    a14 += sw * (float)((qs.w >> 16) & 0xffu);
    a15 += sw * (float)(qs.w >> 24);

    float off = 128.f * sumw;
    uint4 o0, o1;
    o0.x = (uint)f2bf(a00 - off) | ((uint)f2bf(a01 - off) << 16);
    o0.y = (uint)f2bf(a02 - off) | ((uint)f2bf(a03 - off) << 16);
    o0.z = (uint)f2bf(a04 - off) | ((uint)f2bf(a05 - off) << 16);
    o0.w = (uint)f2bf(a06 - off) | ((uint)f2bf(a07 - off) << 16);
    o1.x = (uint)f2bf(a08 - off) | ((uint)f2bf(a09 - off) << 16);
    o1.y = (uint)f2bf(a10 - off) | ((uint)f2bf(a11 - off) << 16);
    o1.z = (uint)f2bf(a12 - off) | ((uint)f2bf(a13 - off) << 16);
    o1.w = (uint)f2bf(a14 - off) | ((uint)f2bf(a15 - off) << 16);
    ((uint4*)z)[node * 16 + l8 * 2]     = o0;
    ((uint4*)z)[node * 16 + l8 * 2 + 1] = o1;
}

// ---------------------------------------------------------------------------
// MFMA GEMM: out = ELU( z@Wc + x@Ws + bc + bsk ), split-bf16 on the x path.
// (round-12 form: wp staged per-ks in LDS)
__global__ __launch_bounds__(256) void gemm_kernel(const unsigned short* __restrict__ zb,
                                                   const float* __restrict__ x,
                                                   const short8* __restrict__ wp,
                                                   const float* __restrict__ bc,
                                                   const float* __restrict__ bsk,
                                                   float* __restrict__ out, int N) {
    __shared__ short8 bsm[1536];   // 3 planes x 8 nt x 64 lanes = 24KB
    const int tid = threadIdx.x;
    const int lane = tid & 63;
    const int wave = tid >> 6;
    const int m = lane & 15;
    const int quad = lane >> 4;
    const int row = blockIdx.x * 64 + wave * 16 + m;
    const bool rowok = row < N;

    f32x4 acc[8];
    #pragma unroll
    for (int i = 0; i < 8; ++i) acc[i] = (f32x4){0.f, 0.f, 0.f, 0.f};

    #pragma unroll
    for (int ks = 0; ks < 4; ++ks) {
        const int k0 = ks * 32 + quad * 8;
        short8 za = {0, 0, 0, 0, 0, 0, 0, 0};
        short8 xa_h = {0, 0, 0, 0, 0, 0, 0, 0};
        short8 xa_l = {0, 0, 0, 0, 0, 0, 0, 0};
        if (rowok) {
            za = ((const short8*)zb)[(row * H + k0) >> 3];
            float4 a = *(const float4*)&x[row * H + k0];
            float4 b = *(const float4*)&x[row * H + k0 + 4];
            float xv[8] = {a.x, a.y, a.z, a.w, b.x, b.y, b.z, b.w};
            #pragma unroll
            for (int j = 0; j < 8; ++j) {
                unsigned short h = f2bf(xv[j]);
                xa_h[j] = (short)h;
                xa_l[j] = (short)f2bf(xv[j] - bf2f(h));
            }
        }
        __syncthreads();
        #pragma unroll
        for (int p = 0; p < 3; ++p) {
            bsm[p * 512 + tid]       = wp[p * 2048 + ks * 512 + tid];
            bsm[p * 512 + 256 + tid] = wp[p * 2048 + ks * 512 + 256 + tid];
        }
        __syncthreads();
        #pragma unroll
        for (int nt = 0; nt < 8; ++nt) {
            short8 bch = bsm[nt * 64 + lane];
            short8 bsh = bsm[512 + nt * 64 + lane];
            short8 bsl = bsm[1024 + nt * 64 + lane];
            acc[nt] = __builtin_amdgcn_mfma_f32_16x16x32_bf16(za, bch, acc[nt], 0, 0, 0);
            acc[nt] = __builtin_amdgcn_mfma_f32_16x16x32_bf16(xa_h, bsh, acc[nt], 0, 0, 0);
            acc[nt] = __builtin_amdgcn_mfma_f32_16x16x32_bf16(xa_l, bsh, acc[nt], 0, 0, 0);
            acc[nt] = __builtin_amdgcn_mfma_f32_16x16x32_bf16(xa_h, bsl, acc[nt], 0, 0, 0);
        }
    }

    const int orow_base = blockIdx.x * 64 + wave * 16 + quad * 4;
    #pragma unroll
    for (int nt = 0; nt < 8; ++nt) {
        int col = nt * 16 + m;
        float bias = bc[col] + bsk[col];
        #pragma unroll
        for (int r = 0; r < 4; ++r) {
            int orow = orow_base + r;
            if (orow < N) {
                float v = acc[nt][r] + bias;
                v = v > 0.f ? v : 0.1f * (__expf(v) - 1.f);
                out[orow * H + col] = v;
            }
        }
    }
}

// ---------------------------------------------------------------------------
extern "C" void kernel_launch(void* const* d_in, const int* in_sizes, int n_in,
                              void* d_out, int out_size, void* d_ws, size_t ws_size,
                              hipStream_t stream) {
    const float* x   = (const float*)d_in[0];
    const int*   ei  = (const int*)d_in[1];
    const float* Wc  = (const float*)d_in[2];
    const float* bc  = (const float*)d_in[3];
    const float* Wsk = (const float*)d_in[4];
    const float* bsk = (const float*)d_in[5];
    float* out = (float*)d_out;

    const int N = in_sizes[0] / H;       // 100000
    const int E = in_sizes[1] / 2;       // 1600000
    const int nbu = (N + BW - 1) / BW;   // 782 coarse buckets (<=1024)
    const int chunk = (E + NB - 1) / NB; // 6250 edges per partition block
    const int qb = (N + 7) / 8;          // quant blocks

    // workspace layout (byte offsets) -- round-10/12 proven map:
    //   0         wp (96KB, pad to 128K)
    //   131072    rstart (N+1 ints)
    //   540672    dinv (N f32)
    //   942080    ainv (N f32)
    //   1343488   selfw (N f32)
    //   1744896   entries (E ints, 6.4MB)
    //   8146944   xq (u8 N*H, 12.8MB)
    //   20971520  z (bf16 N*H, 25.6MB) -- written only by agg; temporaries
    //             below overlay it and are all dead before agg:
    //   20971520  invs (N f32)          [quant -> csrOne]
    //   21371520  cstart (nbu+1)        [p5 -> csrOne]
    //   21374784  btot (nbu)            [p2 -> p5]
    //   21377984  counts (NB*nbu)       [hist -> p2]
    //   22178752  scanned (NB*nbu)      [p2 -> p5]
    //   22979520  tmp (E ints, 6.4MB)   [p5 -> csrOne]
    char* w = (char*)d_ws;
    short8*         wp      = (short8*)w;
    int*            rstart  = (int*)(w + 131072);
    float*          dinv    = (float*)(w + 540672);
    float*          ainv    = (float*)(w + 942080);
    float*          selfw   = (float*)(w + 1343488);
    int*            entries = (int*)(w + 1744896);
    uint*           xq      = (uint*)(w + 8146944);
    unsigned short* z       = (unsigned short*)(w + 20971520);
    float*          invs    = (float*)(w + 20971520);
    int*            cstart  = (int*)(w + 21371520);
    int*            btot    = (int*)(w + 21374784);
    int*            counts  = (int*)(w + 21377984);
    int*            scanned = (int*)(w + 22178752);
    int*            tmp     = (int*)(w + 22979520);

    // quant + W-pack + p1 histogram, fused
    quant_hist_kernel<<<qb + NB, 256, 0, stream>>>(x, Wc, Wsk, ei, xq, invs, wp,
                                                   counts, N, E, nbu, chunk, qb);

    // coalesced tiled scan of counts -> scanned + btot
    p2_scan<<<(nbu + TK - 1) / TK, 256, 0, stream>>>(counts, scanned, btot, nbu);

    p5_scatter<<<NB, 256, 0, stream>>>(ei, btot, scanned, tmp, cstart, E, nbu, chunk);

    // single CSR kernel: metrics + in-bucket sort
    csr_kernel<<<nbu, 256, 0, stream>>>(tmp, cstart, invs, entries, rstart,
                                        dinv, ainv, selfw, N, E);

    // z = sum(w * q[src]) - 128*sumw + selfloop (bf16); octet-per-node
    agg_kernel<<<(N + 31) / 32, 256, 0, stream>>>(entries, rstart, dinv, ainv,
                                                  selfw, xq, z, N);

    // out = ELU(z@Wc + x@Ws + biases)
    gemm_kernel<<<(N + 63) / 64, 256, 0, stream>>>(z, x, wp, bc, bsk, out, N);
}